// Round 9
// baseline (479.867 us; speedup 1.0000x reference)
//
#include <hip/hip_runtime.h>
#include <hip/hip_cooperative_groups.h>
#include <hip/hip_bf16.h>
#include <math.h>

namespace cg = cooperative_groups;

// Problem constants
#define NN  20000
#define NE  50000
#define NE2 100000
#define H   32
#define FN  4
#define FE  2
#define FO  4
#define NL  3

#define FRAGS_PER_LAYER (33 * 2)
#define BVALS_PER_LAYER (FRAGS_PER_LAYER * 512)    // 33792 bf16 per layer (per hi/lo)

// fallback (R3) grid partitions
#define TCHUNKS 196
#define NB_TALL (NL * 32 * TCHUNKS)
#define NB_PREP ((NL * BVALS_PER_LAYER + 255)/256)
#define NB_ZERO (NN * H / 4 / 256)
#define NB_ENC  ((NN + 255)/256)

// cooperative config
#define CGRID 256                                  // 1 block/CU -- co-residency safe
#define EBC   128                                  // edges per tile in coop edge phase
#define TPDC  ((NE + EBC - 1) / EBC)               // 391 tiles per direction
#define NTILES (2 * TPDC)                          // 782

typedef __attribute__((ext_vector_type(8))) short short8;
typedef __attribute__((ext_vector_type(4))) float f32x4;

__device__ __forceinline__ float gelu_f(float x) {
    return 0.5f * x * (1.0f + erff(x * 0.7071067811865476f));
}
__device__ __forceinline__ short f2bf(float x) {
    __hip_bfloat16 b = __float2bfloat16(x);
    return __builtin_bit_cast(short, b);
}
__device__ __forceinline__ float bf2f(short s) {
    __hip_bfloat16 b = __builtin_bit_cast(__hip_bfloat16, s);
    return __bfloat162float(b);
}

struct Params {
    const float *x, *pm;
    const int   *ei;
    const float *ea;
    const float *W_in, *b_in, *mW1, *mb1, *mW2, *mb2;
    const float *eW1, *eb1, *eW2, *eb2;
    const float *Wr, *cb, *gm, *bt;
    const float *dW1, *db1, *dW2, *db2;
    float *out, *h, *agg, *tfull;
    short *Bhi, *Blo;
};

// ===========================================================================
// Cooperative single-kernel pipeline (256 blocks x 256 threads, 1 block/CU)
// ===========================================================================
__global__ __launch_bounds__(256) void fused_all(Params P)
{
    cg::grid_group grid = cg::this_grid();
    __shared__ __align__(16) unsigned char smem[17536];

    const int tid = threadIdx.x;
    const int bid = blockIdx.x;
    const int gid = bid * 256 + tid;
    const int gstride = CGRID * 256;

    // ---------------- Phase 0: encoder | t-gen | W2-prep | zero agg ----------
    {
        // encoder weights -> LDS
        float* sWin = (float*)smem;
        float* sW1  = sWin + FN*H;
        float* sW2  = sW1 + FN*H;
        float* sbin = sW2 + H*H;
        float* sb1  = sbin + H;
        float* sb2  = sb1 + H;
        for (int i = tid; i < FN*H; i += 256) { sWin[i] = P.W_in[i]; sW1[i] = P.mW1[i]; }
        for (int i = tid; i < H*H; i += 256) sW2[i] = P.mW2[i];
        if (tid < H) { sbin[tid] = P.b_in[tid]; sb1[tid] = P.mb1[tid]; sb2[tid] = P.mb2[tid]; }
        __syncthreads();

        // encoder (each thread <=1 node since gstride=65536 > NN)
        for (int n = gid; n < NN; n += gstride) {
            float xv[FN], pv[FN];
#pragma unroll
            for (int i = 0; i < FN; ++i) { xv[i] = P.x[n*FN+i]; pv[i] = P.pm[n*FN+i]; }
            float m[H];
#pragma unroll
            for (int j = 0; j < H; ++j) {
                float a = sb1[j];
#pragma unroll
                for (int i = 0; i < FN; ++i) a += pv[i] * sW1[i*H+j];
                m[j] = gelu_f(a);
            }
#pragma unroll
            for (int j = 0; j < H; ++j) {
                float a = sbin[j] + sb2[j];
#pragma unroll
                for (int i = 0; i < FN; ++i) a += xv[i] * sWin[i*H+j];
                float s = 0.f;
#pragma unroll
                for (int k = 0; k < H; ++k) s += m[k] * sW2[k*H+j];
                P.h[n*H+j] = a + s;
            }
        }

        // t-gen: one float4 (4 edges) per unit
        const int U = NL * 32 * (NE / 4);
        for (int idx = gid; idx < U; idx += gstride) {
            int lk = idx / (NE / 4);
            int e4 = idx - lk * (NE / 4);
            int er = e4 * 4;
            int l = lk >> 5, k = lk & 31;
            float w0 = P.eW1[l*FE*H + k];
            float w1 = P.eW1[l*FE*H + H + k];
            float bb = P.eb1[l*H + k];
            float4 q0 = *(const float4*)(P.ea + (size_t)er*2);
            float4 q1 = *(const float4*)(P.ea + (size_t)er*2 + 4);
            float4 tv;
            tv.x = gelu_f(q0.x * w0 + q0.y * w1 + bb);
            tv.y = gelu_f(q0.z * w0 + q0.w * w1 + bb);
            tv.z = gelu_f(q1.x * w0 + q1.y * w1 + bb);
            tv.w = gelu_f(q1.z * w0 + q1.w * w1 + bb);
            *(float4*)(P.tfull + (size_t)lk * NE + er) = tv;
        }

        // W2 (+b2) -> MFMA B-fragment order, bf16 hi+lo
        for (int idx = gid; idx < NL * BVALS_PER_LAYER; idx += gstride) {
            int layer = idx / BVALS_PER_LAYER;
            int rem   = idx - layer * BVALS_PER_LAYER;
            int f      = rem >> 9;
            int within = rem & 511;
            int step = f >> 1, nt = f & 1;
            int l = within >> 3, j = within & 7;
            int p = ((l >> 4) << 3) + j;
            int n = nt * 16 + (l & 15);
            float v;
            if (step < 32) v = P.eW2[layer * 32768 + step * 1024 + p * 32 + n];
            else           v = P.eb2[layer * 1024 + p * 32 + n];
            short hi = f2bf(v);
            short lo = f2bf(v - bf2f(hi));
            P.Bhi[idx] = hi;
            P.Blo[idx] = lo;
        }

        // zero agg
        float4 z = make_float4(0.f, 0.f, 0.f, 0.f);
        for (int i = gid; i < NN * H / 4; i += gstride)
            ((float4*)P.agg)[i] = z;
    }
    grid.sync();

    // ---------------- Layers ----------------
    for (int l = 0; l < NL; ++l) {
        const float* tfull_l = P.tfull + (size_t)l * 32 * NE;
        const short8* Bh = (const short8*)(P.Bhi + l * BVALS_PER_LAYER);
        const short8* Bl = (const short8*)(P.Blo + l * BVALS_PER_LAYER);

        // ---- edge phase: grid-stride over 782 tiles of 128 edges
        {
            float (*t_lds)[EBC] = (float(*)[EBC])smem;        // 16 KB
            int* src_lds = (int*)(smem + 32 * EBC * 4);       // 512 B
            int* dst_lds = src_lds + EBC;                     // 512 B

            const int wv = tid >> 6, lane = tid & 63;
            const int lg = lane >> 4, lm = lane & 15;
            const int jbase = wv * 32;

            for (int tile = bid; tile < NTILES; tile += CGRID) {
                __syncthreads();
                bool half2 = tile >= TPDC;
                int er_base = (half2 ? tile - TPDC : tile) * EBC;

                if (tid < EBC) {
                    int er = er_base + tid;
                    int erc = er < NE ? er : NE - 1;
                    int s, d;
                    if (half2) { s = P.ei[NE + erc]; d = P.ei[erc]; }
                    else       { s = P.ei[erc];      d = P.ei[NE + erc]; }
                    bool v = er < NE;
                    src_lds[tid] = v ? s : 0;
                    dst_lds[tid] = v ? d : 0;
                }
                {
                    int kq = tid >> 5;
                    int c  = tid & 31;
                    int col = er_base + c * 4;
                    if (col > NE - 4) col = NE - 4;
#pragma unroll
                    for (int q = 0; q < 4; ++q) {
                        int k = q * 8 + kq;
                        *(float4*)&t_lds[k][c * 4] = *(const float4*)(tfull_l + (size_t)k * NE + col);
                    }
                }
                __syncthreads();

                float hs[2][8];
#pragma unroll
                for (int m = 0; m < 2; ++m) {
                    int s = src_lds[jbase + m*16 + lm];
                    const float4* hp = (const float4*)(P.h + (size_t)s*H + lg*8);
                    float4 u0 = hp[0], u1 = hp[1];
                    hs[m][0]=u0.x; hs[m][1]=u0.y; hs[m][2]=u0.z; hs[m][3]=u0.w;
                    hs[m][4]=u1.x; hs[m][5]=u1.y; hs[m][6]=u1.z; hs[m][7]=u1.w;
                }

                f32x4 acc[2][2];
#pragma unroll
                for (int m = 0; m < 2; ++m) {
                    acc[m][0] = (f32x4){0.f,0.f,0.f,0.f};
                    acc[m][1] = (f32x4){0.f,0.f,0.f,0.f};
                }

                short8 cb0h = Bh[lane], cb1h = Bh[64 + lane];
                short8 cb0l = Bl[lane], cb1l = Bl[64 + lane];
                short8 nb0h = cb0h, nb1h = cb1h, nb0l = cb0l, nb1l = cb1l;

#pragma unroll 1
                for (int step = 0; step < 33; ++step) {
                    if (step < 32) {
                        int fo = (step + 1) * 128 + lane;
                        nb0h = Bh[fo]; nb1h = Bh[fo + 64];
                        nb0l = Bl[fo]; nb1l = Bl[fo + 64];
                    }
#pragma unroll
                    for (int m = 0; m < 2; ++m) {
                        float tv = (step < 32) ? t_lds[step][jbase + m*16 + lm] : 1.0f;
                        short8 a;
#pragma unroll
                        for (int j = 0; j < 8; ++j) a[j] = f2bf(tv * hs[m][j]);
                        acc[m][0] = __builtin_amdgcn_mfma_f32_16x16x32_bf16(a, cb0h, acc[m][0], 0, 0, 0);
                        acc[m][0] = __builtin_amdgcn_mfma_f32_16x16x32_bf16(a, cb0l, acc[m][0], 0, 0, 0);
                        acc[m][1] = __builtin_amdgcn_mfma_f32_16x16x32_bf16(a, cb1h, acc[m][1], 0, 0, 0);
                        acc[m][1] = __builtin_amdgcn_mfma_f32_16x16x32_bf16(a, cb1l, acc[m][1], 0, 0, 0);
                    }
                    cb0h = nb0h; cb1h = nb1h; cb0l = nb0l; cb1l = nb1l;
                }

#pragma unroll
                for (int m = 0; m < 2; ++m) {
#pragma unroll
                    for (int r = 0; r < 4; ++r) {
                        int erow = jbase + m*16 + lg*4 + r;
                        if (er_base + erow < NE) {
                            int d = dst_lds[erow];
                            atomicAdd(P.agg + (size_t)d*H + lm,      acc[m][0][r]);
                            atomicAdd(P.agg + (size_t)d*H + 16 + lm, acc[m][1][r]);
                        }
                    }
                }
            }
        }
        grid.sync();

        // ---- node phase
        {
            float* swr  = (float*)smem;
            float* sW1d = swr + H*H;
            float* sW2d = sW1d + H*H;
            float* scb  = sW2d + H*FO;
            float* sg   = scb + H;
            float* sb   = sg + H;
            float* sb1d = sb + H;
            float* sb2d = sb1d + H;
            const int last = (l == NL - 1);

            for (int i = tid; i < H*H; i += 256) { swr[i] = P.Wr[l*H*H + i]; sW1d[i] = P.dW1[i]; }
            for (int i = tid; i < H*FO; i += 256) sW2d[i] = P.dW2[i];
            if (tid < H) { scb[tid] = P.cb[l*H + tid]; sg[tid] = P.gm[l*H + tid];
                           sb[tid] = P.bt[l*H + tid];  sb1d[tid] = P.db1[tid]; }
            if (tid < FO) sb2d[tid] = P.db2[tid];
            __syncthreads();

            for (int n = gid; n < NN; n += gstride) {
                float hv[H], hc[H];
#pragma unroll
                for (int q = 0; q < 8; ++q) {
                    float4 v = ((const float4*)(P.h + (size_t)n*H))[q];
                    hv[q*4+0]=v.x; hv[q*4+1]=v.y; hv[q*4+2]=v.z; hv[q*4+3]=v.w;
                    float4 g = ((const float4*)(P.agg + (size_t)n*H))[q];
                    hc[q*4+0]=g.x; hc[q*4+1]=g.y; hc[q*4+2]=g.z; hc[q*4+3]=g.w;
                }
#pragma unroll
                for (int o = 0; o < H; ++o) hc[o] += scb[o];
#pragma unroll
                for (int k = 0; k < H; ++k) {
                    float hk = hv[k];
#pragma unroll
                    for (int o = 0; o < H; ++o) hc[o] += hk * swr[k*H+o];
                }
                float mu = 0.f;
#pragma unroll
                for (int o = 0; o < H; ++o) mu += hc[o];
                mu *= (1.0f/H);
                float var = 0.f;
#pragma unroll
                for (int o = 0; o < H; ++o) { float d = hc[o]-mu; var += d*d; }
                var *= (1.0f/H);
                float rs = rsqrtf(var + 1e-5f);
#pragma unroll
                for (int o = 0; o < H; ++o) {
                    float hn = (hc[o]-mu)*rs*sg[o] + sb[o];
                    hv[o] += gelu_f(hn);
                }

                if (!last) {
#pragma unroll
                    for (int q = 0; q < 8; ++q) {
                        ((float4*)(P.h + (size_t)n*H))[q]   = make_float4(hv[q*4+0], hv[q*4+1], hv[q*4+2], hv[q*4+3]);
                        ((float4*)(P.agg + (size_t)n*H))[q] = make_float4(0.f, 0.f, 0.f, 0.f);
                    }
                } else {
                    float g[H];
#pragma unroll
                    for (int j = 0; j < H; ++j) {
                        float a = sb1d[j];
#pragma unroll
                        for (int k = 0; k < H; ++k) a += hv[k] * sW1d[k*H+j];
                        g[j] = gelu_f(a);
                    }
#pragma unroll
                    for (int o = 0; o < FO; ++o) {
                        float a = sb2d[o];
#pragma unroll
                        for (int k = 0; k < H; ++k) a += g[k] * sW2d[k*FO+o];
                        P.out[n*FO+o] = a;
                    }
                }
            }
        }
        if (l < NL - 1) grid.sync();
    }
}

// ===========================================================================
// Fallback pipeline (verbatim R3 -- verified 181 us / absmax 0.03125)
// ===========================================================================
__global__ __launch_bounds__(256) void prologue(
    const float* __restrict__ x, const float* __restrict__ pm,
    const float* __restrict__ W_in, const float* __restrict__ b_in,
    const float* __restrict__ mW1, const float* __restrict__ mb1,
    const float* __restrict__ mW2, const float* __restrict__ mb2,
    const float* __restrict__ eW1, const float* __restrict__ eb1,
    const float* __restrict__ eW2, const float* __restrict__ eb2,
    const float* __restrict__ ea,
    float* __restrict__ h, float* __restrict__ agg,
    short* __restrict__ Bhi, short* __restrict__ Blo,
    float* __restrict__ tfull)
{
    int bid = blockIdx.x;
    int tid = threadIdx.x;

    if (bid < NB_TALL) {
        int l     = bid / (32 * TCHUNKS);
        int rem   = bid - l * 32 * TCHUNKS;
        int k     = rem / TCHUNKS;
        int chunk = rem - k * TCHUNKS;
        int er    = chunk * 256 + tid;
        float w0 = eW1[l*FE*H + k];
        float w1 = eW1[l*FE*H + H + k];
        float bb = eb1[l*H + k];
        if (er < NE) {
            float tv = gelu_f(ea[er*2] * w0 + ea[er*2+1] * w1 + bb);
            tfull[(l*32 + k) * NE + er] = tv;
        }
        return;
    }
    bid -= NB_TALL;

    if (bid < NB_PREP) {
        int idx = bid * 256 + tid;
        if (idx >= NL * BVALS_PER_LAYER) return;
        int layer = idx / BVALS_PER_LAYER;
        int rem   = idx - layer * BVALS_PER_LAYER;
        int f      = rem >> 9;
        int within = rem & 511;
        int step = f >> 1, nt = f & 1;
        int l = within >> 3, j = within & 7;
        int p = ((l >> 4) << 3) + j;
        int n = nt * 16 + (l & 15);
        float v;
        if (step < 32) v = eW2[layer * 32768 + step * 1024 + p * 32 + n];
        else           v = eb2[layer * 1024 + p * 32 + n];
        short hi = f2bf(v);
        short lo = f2bf(v - bf2f(hi));
        Bhi[idx] = hi;
        Blo[idx] = lo;
        return;
    }
    bid -= NB_PREP;

    if (bid < NB_ZERO) {
        int i = bid * 256 + tid;
        ((float4*)agg)[i] = make_float4(0.f, 0.f, 0.f, 0.f);
        return;
    }
    bid -= NB_ZERO;

    __shared__ float sWin[FN*H], sW1[FN*H], sW2[H*H];
    __shared__ float sbin[H], sb1[H], sb2[H];
    for (int i = tid; i < FN*H; i += 256) { sWin[i] = W_in[i]; sW1[i] = mW1[i]; }
    for (int i = tid; i < H*H; i += 256) sW2[i] = mW2[i];
    if (tid < H) { sbin[tid] = b_in[tid]; sb1[tid] = mb1[tid]; sb2[tid] = mb2[tid]; }
    __syncthreads();
    int n = bid * 256 + tid;
    if (n >= NN) return;
    float xv[FN], pv[FN];
#pragma unroll
    for (int i = 0; i < FN; ++i) { xv[i] = x[n*FN+i]; pv[i] = pm[n*FN+i]; }
    float m[H];
#pragma unroll
    for (int j = 0; j < H; ++j) {
        float a = sb1[j];
#pragma unroll
        for (int i = 0; i < FN; ++i) a += pv[i] * sW1[i*H+j];
        m[j] = gelu_f(a);
    }
#pragma unroll
    for (int j = 0; j < H; ++j) {
        float a = sbin[j] + sb2[j];
#pragma unroll
        for (int i = 0; i < FN; ++i) a += xv[i] * sWin[i*H+j];
        float s = 0.f;
#pragma unroll
        for (int k = 0; k < H; ++k) s += m[k] * sW2[k*H+j];
        h[n*H+j] = a + s;
    }
}

__global__ __launch_bounds__(256) void edge_pass(
    const float* __restrict__ h,
    const int* __restrict__ ei,
    const float* __restrict__ tfull_l,
    const short* __restrict__ Bhi,
    const short* __restrict__ Blo,
    float* __restrict__ agg)
{
    __shared__ float t_lds[32][256];
    __shared__ int src_lds[256], dst_lds[256];

    int tid = threadIdx.x;
    int bid = blockIdx.x;
    bool half2 = bid >= TCHUNKS;
    int er_base = (half2 ? bid - TCHUNKS : bid) * 256;

    {
        int er = er_base + tid;
        int erc = er < NE ? er : NE - 1;
        int s, d;
        if (half2) { s = ei[NE + erc]; d = ei[erc]; }
        else       { s = ei[erc];      d = ei[NE + erc]; }
        bool v = er < NE;
        src_lds[tid] = v ? s : 0;
        dst_lds[tid] = v ? d : 0;
    }
    {
        int c  = tid & 63;
        int kq = tid >> 6;
        int col = er_base + c * 4;
        if (col > NE - 4) col = NE - 4;
#pragma unroll
        for (int q = 0; q < 8; ++q) {
            int k = q * 4 + kq;
            float4 tv = *(const float4*)(tfull_l + k * NE + col);
            *(float4*)&t_lds[k][c * 4] = tv;
        }
    }
    __syncthreads();

    int wv = tid >> 6, lane = tid & 63;
    int lg = lane >> 4, lm = lane & 15;
    int jbase = wv * 64;

    float hs[4][8];
#pragma unroll
    for (int m = 0; m < 4; ++m) {
        int s = src_lds[jbase + m*16 + lm];
        const float4* hp = (const float4*)(h + s*H + lg*8);
        float4 u0 = hp[0], u1 = hp[1];
        hs[m][0]=u0.x; hs[m][1]=u0.y; hs[m][2]=u0.z; hs[m][3]=u0.w;
        hs[m][4]=u1.x; hs[m][5]=u1.y; hs[m][6]=u1.z; hs[m][7]=u1.w;
    }

    f32x4 acc[4][2];
#pragma unroll
    for (int m = 0; m < 4; ++m) {
        acc[m][0] = (f32x4){0.f,0.f,0.f,0.f};
        acc[m][1] = (f32x4){0.f,0.f,0.f,0.f};
    }

    const short8* Bh = (const short8*)Bhi;
    const short8* Bl = (const short8*)Blo;
    short8 cb0h = Bh[lane], cb1h = Bh[64 + lane];
    short8 cb0l = Bl[lane], cb1l = Bl[64 + lane];
    short8 nb0h = cb0h, nb1h = cb1h, nb0l = cb0l, nb1l = cb1l;

#pragma unroll 1
    for (int step = 0; step < 33; ++step) {
        if (step < 32) {
            int fo = (step + 1) * 128 + lane;
            nb0h = Bh[fo]; nb1h = Bh[fo + 64];
            nb0l = Bl[fo]; nb1l = Bl[fo + 64];
        }
#pragma unroll
        for (int m = 0; m < 4; ++m) {
            float tv = (step < 32) ? t_lds[step][jbase + m*16 + lm] : 1.0f;
            short8 a;
#pragma unroll
            for (int j = 0; j < 8; ++j) a[j] = f2bf(tv * hs[m][j]);
            acc[m][0] = __builtin_amdgcn_mfma_f32_16x16x32_bf16(a, cb0h, acc[m][0], 0, 0, 0);
            acc[m][0] = __builtin_amdgcn_mfma_f32_16x16x32_bf16(a, cb0l, acc[m][0], 0, 0, 0);
            acc[m][1] = __builtin_amdgcn_mfma_f32_16x16x32_bf16(a, cb1h, acc[m][1], 0, 0, 0);
            acc[m][1] = __builtin_amdgcn_mfma_f32_16x16x32_bf16(a, cb1l, acc[m][1], 0, 0, 0);
        }
        cb0h = nb0h; cb1h = nb1h; cb0l = nb0l; cb1l = nb1l;
    }

#pragma unroll
    for (int m = 0; m < 4; ++m) {
#pragma unroll
        for (int r = 0; r < 4; ++r) {
            int erow = jbase + m*16 + lg*4 + r;
            if (er_base + erow < NE) {
                int d = dst_lds[erow];
                atomicAdd(agg + d*H + lm,      acc[m][0][r]);
                atomicAdd(agg + d*H + 16 + lm, acc[m][1][r]);
            }
        }
    }
}

__global__ __launch_bounds__(256) void node_update(
    float* __restrict__ h, float* __restrict__ agg,
    const float* __restrict__ wr, const float* __restrict__ cb,
    const float* __restrict__ gamma, const float* __restrict__ beta,
    const float* __restrict__ dW1, const float* __restrict__ db1,
    const float* __restrict__ dW2, const float* __restrict__ db2,
    float* __restrict__ out, int last)
{
    __shared__ float swr[H*H], sW1d[H*H], sW2d[H*FO];
    __shared__ float scb[H], sg[H], sb[H], sb1d[H], sb2d[FO];
    int tid = threadIdx.x;
    for (int i = tid; i < H*H; i += 256) { swr[i] = wr[i]; sW1d[i] = dW1[i]; }
    for (int i = tid; i < H*FO; i += 256) sW2d[i] = dW2[i];
    if (tid < H) { scb[tid] = cb[tid]; sg[tid] = gamma[tid]; sb[tid] = beta[tid]; sb1d[tid] = db1[tid]; }
    if (tid < FO) sb2d[tid] = db2[tid];
    __syncthreads();
    int n = blockIdx.x * 256 + tid;
    if (n >= NN) return;

    float hv[H], hc[H];
#pragma unroll
    for (int q = 0; q < 8; ++q) {
        float4 v = ((const float4*)(h + n*H))[q];
        hv[q*4+0]=v.x; hv[q*4+1]=v.y; hv[q*4+2]=v.z; hv[q*4+3]=v.w;
        float4 g = ((const float4*)(agg + n*H))[q];
        hc[q*4+0]=g.x; hc[q*4+1]=g.y; hc[q*4+2]=g.z; hc[q*4+3]=g.w;
    }
#pragma unroll
    for (int o = 0; o < H; ++o) hc[o] += scb[o];
#pragma unroll
    for (int k = 0; k < H; ++k) {
        float hk = hv[k];
#pragma unroll
        for (int o = 0; o < H; ++o) hc[o] += hk * swr[k*H+o];
    }
    float mu = 0.f;
#pragma unroll
    for (int o = 0; o < H; ++o) mu += hc[o];
    mu *= (1.0f/H);
    float var = 0.f;
#pragma unroll
    for (int o = 0; o < H; ++o) { float d = hc[o]-mu; var += d*d; }
    var *= (1.0f/H);
    float rs = rsqrtf(var + 1e-5f);
#pragma unroll
    for (int o = 0; o < H; ++o) {
        float hn = (hc[o]-mu)*rs*sg[o] + sb[o];
        hv[o] += gelu_f(hn);
    }

    if (!last) {
#pragma unroll
        for (int q = 0; q < 8; ++q) {
            ((float4*)(h + n*H))[q]   = make_float4(hv[q*4+0], hv[q*4+1], hv[q*4+2], hv[q*4+3]);
            ((float4*)(agg + n*H))[q] = make_float4(0.f, 0.f, 0.f, 0.f);
        }
    } else {
        float g[H];
#pragma unroll
        for (int j = 0; j < H; ++j) {
            float a = sb1d[j];
#pragma unroll
            for (int k = 0; k < H; ++k) a += hv[k] * sW1d[k*H+j];
            g[j] = gelu_f(a);
        }
#pragma unroll
        for (int o = 0; o < FO; ++o) {
            float a = sb2d[o];
#pragma unroll
            for (int k = 0; k < H; ++k) a += g[k] * sW2d[k*FO+o];
            out[n*FO+o] = a;
        }
    }
}

// ---------------------------------------------------------------------------
extern "C" void kernel_launch(void* const* d_in, const int* in_sizes, int n_in,
                              void* d_out, int out_size, void* d_ws, size_t ws_size,
                              hipStream_t stream)
{
    Params P;
    P.x    = (const float*)d_in[0];
    P.pm   = (const float*)d_in[1];
    P.ei   = (const int*)d_in[2];
    P.ea   = (const float*)d_in[3];
    P.W_in = (const float*)d_in[4];
    P.b_in = (const float*)d_in[5];
    P.mW1  = (const float*)d_in[6];
    P.mb1  = (const float*)d_in[7];
    P.mW2  = (const float*)d_in[8];
    P.mb2  = (const float*)d_in[9];
    P.eW1  = (const float*)d_in[10];
    P.eb1  = (const float*)d_in[11];
    P.eW2  = (const float*)d_in[12];
    P.eb2  = (const float*)d_in[13];
    P.Wr   = (const float*)d_in[14];
    P.cb   = (const float*)d_in[15];
    P.gm   = (const float*)d_in[16];
    P.bt   = (const float*)d_in[17];
    P.dW1  = (const float*)d_in[18];
    P.db1  = (const float*)d_in[19];
    P.dW2  = (const float*)d_in[20];
    P.db2  = (const float*)d_in[21];
    P.out  = (float*)d_out;

    P.h     = (float*)d_ws;
    P.agg   = P.h + NN*H;
    P.tfull = P.agg + NN*H;
    P.Bhi   = (short*)(P.tfull + NL*32*NE);
    P.Blo   = P.Bhi + NL * BVALS_PER_LAYER;

    void* args[] = { &P };
    hipError_t err = hipLaunchCooperativeKernel((const void*)fused_all,
                                                dim3(CGRID), dim3(256),
                                                args, 0, stream);
    if (err != hipSuccess) {
        // fallback: verified multi-kernel pipeline (R3)
        prologue<<<NB_TALL + NB_PREP + NB_ZERO + NB_ENC, 256, 0, stream>>>(
            P.x, P.pm, P.W_in, P.b_in, P.mW1, P.mb1, P.mW2, P.mb2,
            P.eW1, P.eb1, P.eW2, P.eb2, P.ea,
            P.h, P.agg, P.Bhi, P.Blo, P.tfull);
        for (int l = 0; l < NL; ++l) {
            edge_pass<<<2*TCHUNKS, 256, 0, stream>>>(
                P.h, P.ei, P.tfull + (size_t)l*32*NE,
                P.Bhi + l*BVALS_PER_LAYER, P.Blo + l*BVALS_PER_LAYER, P.agg);
            node_update<<<(NN + 255)/256, 256, 0, stream>>>(
                P.h, P.agg, P.Wr + l*H*H, P.cb + l*H, P.gm + l*H, P.bt + l*H,
                P.dW1, P.db1, P.dW2, P.db2, P.out, l == NL-1);
        }
    }
}

// Round 10
// 155.176 us; speedup vs baseline: 3.0924x; 3.0924x over previous
//
#include <hip/hip_runtime.h>
#include <hip/hip_bf16.h>
#include <math.h>

// Problem constants (from reference)
#define NN  20000      // nodes
#define NE  50000      // directed edges (undirected -> 2*NE)
#define NE2 100000
#define H   32
#define FN  4
#define FE  2
#define FO  4
#define NL  3

#define FRAGS_PER_LAYER (33 * 2)                   // 33 K-steps x 2 n-tiles
#define BVALS_PER_LAYER (FRAGS_PER_LAYER * 512)    // 33792 bf16 per layer (hi only now)

#define NB_PREP ((NL * BVALS_PER_LAYER + 255)/256)  // 396
#define NB_ZERO (NN * H / 4 / 256)                  // 625
#define NB_ENC  ((NN + 255)/256)                    // 79

#define TCHUNKS 196                                 // 256-edge tiles per direction
#define EB      256

typedef __attribute__((ext_vector_type(8))) short short8;
typedef __attribute__((ext_vector_type(4))) float f32x4;

__device__ __forceinline__ float gelu_f(float x) {
    return 0.5f * x * (1.0f + erff(x * 0.7071067811865476f));
}
__device__ __forceinline__ short f2bf(float x) {
    __hip_bfloat16 b = __float2bfloat16(x);
    return __builtin_bit_cast(short, b);
}

// ---------------------------------------------------------------------------
// Fused prologue: [prep_bfrag | zero_agg | encoder] by blockIdx range.
// (t-gen removed: t is now computed inside edge_pass)
// ---------------------------------------------------------------------------
__global__ __launch_bounds__(256) void prologue(
    const float* __restrict__ x, const float* __restrict__ pm,
    const float* __restrict__ W_in, const float* __restrict__ b_in,
    const float* __restrict__ mW1, const float* __restrict__ mb1,
    const float* __restrict__ mW2, const float* __restrict__ mb2,
    const float* __restrict__ eW2, const float* __restrict__ eb2,
    float* __restrict__ h, float* __restrict__ agg,
    short* __restrict__ Bhi)
{
    int bid = blockIdx.x;
    int tid = threadIdx.x;

    if (bid < NB_PREP) {
        // ---- prep_bfrag: W2 (+b2 as 33rd step) -> MFMA B-fragment order (bf16)
        int idx = bid * 256 + tid;
        if (idx >= NL * BVALS_PER_LAYER) return;
        int layer = idx / BVALS_PER_LAYER;
        int rem   = idx - layer * BVALS_PER_LAYER;
        int f      = rem >> 9;
        int within = rem & 511;
        int step = f >> 1, nt = f & 1;
        int l = within >> 3, j = within & 7;
        int p = ((l >> 4) << 3) + j;       // K-slot within step == h index
        int n = nt * 16 + (l & 15);        // output column
        float v;
        if (step < 32) v = eW2[layer * 32768 + step * 1024 + p * 32 + n];
        else           v = eb2[layer * 1024 + p * 32 + n];
        Bhi[idx] = f2bf(v);
        return;
    }
    bid -= NB_PREP;

    if (bid < NB_ZERO) {
        int i = bid * 256 + tid;
        ((float4*)agg)[i] = make_float4(0.f, 0.f, 0.f, 0.f);
        return;
    }
    bid -= NB_ZERO;

    // ---- encoder: h = x@W_in + b_in + gelu(pm@mW1+mb1)@mW2 + mb2
    __shared__ float sWin[FN*H], sW1[FN*H], sW2[H*H];
    __shared__ float sbin[H], sb1[H], sb2[H];
    for (int i = tid; i < FN*H; i += 256) { sWin[i] = W_in[i]; sW1[i] = mW1[i]; }
    for (int i = tid; i < H*H; i += 256) sW2[i] = mW2[i];
    if (tid < H) { sbin[tid] = b_in[tid]; sb1[tid] = mb1[tid]; sb2[tid] = mb2[tid]; }
    __syncthreads();
    int n = bid * 256 + tid;
    if (n >= NN) return;
    float xv[FN], pv[FN];
#pragma unroll
    for (int i = 0; i < FN; ++i) { xv[i] = x[n*FN+i]; pv[i] = pm[n*FN+i]; }
    float m[H];
#pragma unroll
    for (int j = 0; j < H; ++j) {
        float a = sb1[j];
#pragma unroll
        for (int i = 0; i < FN; ++i) a += pv[i] * sW1[i*H+j];
        m[j] = gelu_f(a);
    }
#pragma unroll
    for (int j = 0; j < H; ++j) {
        float a = sbin[j] + sb2[j];
#pragma unroll
        for (int i = 0; i < FN; ++i) a += xv[i] * sWin[i*H+j];
        float s = 0.f;
#pragma unroll
        for (int k = 0; k < H; ++k) s += m[k] * sW2[k*H+j];
        h[n*H+j] = a + s;
    }
}

// ---------------------------------------------------------------------------
// Edge pass: 256 threads = 4 waves; 64 edges per wave (4 MFMA M-tiles).
// t computed IN-KERNEL (no tfull stream); B = bf16 hi only, prefetched 2
// steps deep (3-buffer register rotation -> 4 loads in flight covers L2-miss
// latency). atomicAdd scatter into agg[dst].
// ---------------------------------------------------------------------------
__global__ __launch_bounds__(256) void edge_pass(
    const float* __restrict__ h,
    const int* __restrict__ ei,           // [2, NE] int32
    const float* __restrict__ ea,         // [NE, 2]
    const float* __restrict__ w1,         // eW1 + l*FE*H : [2][32]
    const float* __restrict__ b1,         // eb1 + l*H    : [32]
    const short* __restrict__ Bhi,        // layer fragment stream (bf16)
    float* __restrict__ agg)              // [NN, 32]
{
    __shared__ float t_lds[32][EB];       // 32 KB  [k][edge-in-block]
    __shared__ int src_lds[EB], dst_lds[EB];
    __shared__ float sw[3*H];             // w1 row0, w1 row1, b1

    int tid = threadIdx.x;
    int bid = blockIdx.x;
    bool half2 = bid >= TCHUNKS;
    int er_base = (half2 ? bid - TCHUNKS : bid) * EB;

    if (tid < H) {
        sw[tid]       = w1[tid];
        sw[H + tid]   = w1[H + tid];
        sw[2*H + tid] = b1[tid];
    }
    {   // src/dst for this block's 256 edges
        int er = er_base + tid;
        int erc = er < NE ? er : NE - 1;
        int s, d;
        if (half2) { s = ei[NE + erc]; d = ei[erc]; }
        else       { s = ei[erc];      d = ei[NE + erc]; }
        bool v = er < NE;
        src_lds[tid] = v ? s : 0;
        dst_lds[tid] = v ? d : 0;
    }
    __syncthreads();

    {   // t-gen, all threads parallel: t[k][tid] = gelu(ea[er]@w1 + b1)[k]
        int er = er_base + tid;
        int erc = er < NE ? er : NE - 1;
        float2 av = *(const float2*)(ea + (size_t)erc * 2);
#pragma unroll 8
        for (int k = 0; k < 32; ++k) {
            t_lds[k][tid] = gelu_f(av.x * sw[k] + av.y * sw[H + k] + sw[2*H + k]);
        }
    }
    __syncthreads();

    int wv = tid >> 6, lane = tid & 63;
    int lg = lane >> 4, lm = lane & 15;
    int jbase = wv * 64;

    // Per-lane h[src] slice: 8 f32 features for each of 4 M-tile edges.
    float hs[4][8];
#pragma unroll
    for (int m = 0; m < 4; ++m) {
        int s = src_lds[jbase + m*16 + lm];
        const float4* hp = (const float4*)(h + (size_t)s*H + lg*8);
        float4 u0 = hp[0], u1 = hp[1];
        hs[m][0]=u0.x; hs[m][1]=u0.y; hs[m][2]=u0.z; hs[m][3]=u0.w;
        hs[m][4]=u1.x; hs[m][5]=u1.y; hs[m][6]=u1.z; hs[m][7]=u1.w;
    }

    f32x4 acc[4][2];
#pragma unroll
    for (int m = 0; m < 4; ++m) {
        acc[m][0] = (f32x4){0.f,0.f,0.f,0.f};
        acc[m][1] = (f32x4){0.f,0.f,0.f,0.f};
    }

    // B fragments, 2-step-deep register pipeline: A=step s, B=s+1, C=s+2.
    const short8* F = (const short8*)Bhi;     // frag(step,nt) = F[step*128 + nt*64 + lane]
    short8 A0 = F[lane],        A1 = F[64 + lane];
    short8 B0 = F[128 + lane],  B1 = F[192 + lane];
    short8 C0, C1;

#pragma unroll 1
    for (int step = 0; step < 33; ++step) {
        if (step + 2 <= 32) {                 // issue loads for step+2
            int fo = (step + 2) * 128 + lane;
            C0 = F[fo]; C1 = F[fo + 64];
        }
#pragma unroll
        for (int m = 0; m < 4; ++m) {
            float tv = (step < 32) ? t_lds[step][jbase + m*16 + lm] : 1.0f;
            short8 a;
#pragma unroll
            for (int j = 0; j < 8; ++j) a[j] = f2bf(tv * hs[m][j]);
            acc[m][0] = __builtin_amdgcn_mfma_f32_16x16x32_bf16(a, A0, acc[m][0], 0, 0, 0);
            acc[m][1] = __builtin_amdgcn_mfma_f32_16x16x32_bf16(a, A1, acc[m][1], 0, 0, 0);
        }
        A0 = B0; A1 = B1; B0 = C0; B1 = C1;
    }

    // C/D layout: col = lane&15, row = (lane>>4)*4 + reg
#pragma unroll
    for (int m = 0; m < 4; ++m) {
#pragma unroll
        for (int r = 0; r < 4; ++r) {
            int erow = jbase + m*16 + lg*4 + r;
            if (er_base + erow < NE) {
                int d = dst_lds[erow];
                atomicAdd(agg + (size_t)d*H + lm,      acc[m][0][r]);
                atomicAdd(agg + (size_t)d*H + 16 + lm, acc[m][1][r]);
            }
        }
    }
}

// ---------------------------------------------------------------------------
// Node update: hc = agg + h@Wr + cb; LayerNorm; h += gelu(hn).
// Non-last: writes h, re-zeros agg. Last: fuses decoder, writes out.
// ---------------------------------------------------------------------------
__global__ __launch_bounds__(256) void node_update(
    float* __restrict__ h, float* __restrict__ agg,
    const float* __restrict__ wr, const float* __restrict__ cb,
    const float* __restrict__ gamma, const float* __restrict__ beta,
    const float* __restrict__ dW1, const float* __restrict__ db1,
    const float* __restrict__ dW2, const float* __restrict__ db2,
    float* __restrict__ out, int last)
{
    __shared__ float swr[H*H], sW1d[H*H], sW2d[H*FO];
    __shared__ float scb[H], sg[H], sb[H], sb1d[H], sb2d[FO];
    int tid = threadIdx.x;
    for (int i = tid; i < H*H; i += 256) { swr[i] = wr[i]; sW1d[i] = dW1[i]; }
    for (int i = tid; i < H*FO; i += 256) sW2d[i] = dW2[i];
    if (tid < H) { scb[tid] = cb[tid]; sg[tid] = gamma[tid]; sb[tid] = beta[tid]; sb1d[tid] = db1[tid]; }
    if (tid < FO) sb2d[tid] = db2[tid];
    __syncthreads();
    int n = blockIdx.x * 256 + tid;
    if (n >= NN) return;

    float hv[H], hc[H];
#pragma unroll
    for (int q = 0; q < 8; ++q) {
        float4 v = ((const float4*)(h + n*H))[q];
        hv[q*4+0]=v.x; hv[q*4+1]=v.y; hv[q*4+2]=v.z; hv[q*4+3]=v.w;
        float4 g = ((const float4*)(agg + n*H))[q];
        hc[q*4+0]=g.x; hc[q*4+1]=g.y; hc[q*4+2]=g.z; hc[q*4+3]=g.w;
    }
#pragma unroll
    for (int o = 0; o < H; ++o) hc[o] += scb[o];
#pragma unroll
    for (int k = 0; k < H; ++k) {
        float hk = hv[k];
#pragma unroll
        for (int o = 0; o < H; ++o) hc[o] += hk * swr[k*H+o];
    }
    float mu = 0.f;
#pragma unroll
    for (int o = 0; o < H; ++o) mu += hc[o];
    mu *= (1.0f/H);
    float var = 0.f;
#pragma unroll
    for (int o = 0; o < H; ++o) { float d = hc[o]-mu; var += d*d; }
    var *= (1.0f/H);
    float rs = rsqrtf(var + 1e-5f);
#pragma unroll
    for (int o = 0; o < H; ++o) {
        float hn = (hc[o]-mu)*rs*sg[o] + sb[o];
        hv[o] += gelu_f(hn);
    }

    if (!last) {
#pragma unroll
        for (int q = 0; q < 8; ++q) {
            ((float4*)(h + n*H))[q]   = make_float4(hv[q*4+0], hv[q*4+1], hv[q*4+2], hv[q*4+3]);
            ((float4*)(agg + n*H))[q] = make_float4(0.f, 0.f, 0.f, 0.f);
        }
    } else {
        // fused decoder: out = gelu(hv@dW1+db1)@dW2 + db2
        float g[H];
#pragma unroll
        for (int j = 0; j < H; ++j) {
            float a = sb1d[j];
#pragma unroll
            for (int k = 0; k < H; ++k) a += hv[k] * sW1d[k*H+j];
            g[j] = gelu_f(a);
        }
#pragma unroll
        for (int o = 0; o < FO; ++o) {
            float a = sb2d[o];
#pragma unroll
            for (int k = 0; k < H; ++k) a += g[k] * sW2d[k*FO+o];
            out[n*FO+o] = a;
        }
    }
}

// ---------------------------------------------------------------------------
extern "C" void kernel_launch(void* const* d_in, const int* in_sizes, int n_in,
                              void* d_out, int out_size, void* d_ws, size_t ws_size,
                              hipStream_t stream)
{
    const float* x    = (const float*)d_in[0];
    const float* pm   = (const float*)d_in[1];
    const int*   ei   = (const int*)d_in[2];      // int inputs arrive as int32
    const float* ea   = (const float*)d_in[3];
    const float* W_in = (const float*)d_in[4];
    const float* b_in = (const float*)d_in[5];
    const float* mW1  = (const float*)d_in[6];
    const float* mb1  = (const float*)d_in[7];
    const float* mW2  = (const float*)d_in[8];
    const float* mb2  = (const float*)d_in[9];
    const float* eW1  = (const float*)d_in[10];
    const float* eb1  = (const float*)d_in[11];
    const float* eW2  = (const float*)d_in[12];
    const float* eb2  = (const float*)d_in[13];
    const float* Wr   = (const float*)d_in[14];
    const float* cb   = (const float*)d_in[15];
    const float* gm   = (const float*)d_in[16];
    const float* bt   = (const float*)d_in[17];
    const float* dW1  = (const float*)d_in[18];
    const float* db1  = (const float*)d_in[19];
    const float* dW2  = (const float*)d_in[20];
    const float* db2  = (const float*)d_in[21];
    float* out = (float*)d_out;

    float* h   = (float*)d_ws;                    // NN*H f32
    float* agg = h + NN*H;                        // NN*H f32
    short* Bhi = (short*)(agg + NN*H);            // NL*33792 bf16

    prologue<<<NB_PREP + NB_ZERO + NB_ENC, 256, 0, stream>>>(
        x, pm, W_in, b_in, mW1, mb1, mW2, mb2, eW2, eb2, h, agg, Bhi);

    for (int l = 0; l < NL; ++l) {
        edge_pass<<<2*TCHUNKS, 256, 0, stream>>>(
            h, ei, ea, eW1 + l*FE*H, eb1 + l*H,
            Bhi + l*BVALS_PER_LAYER, agg);
        node_update<<<(NN + 255)/256, 256, 0, stream>>>(
            h, agg, Wr + l*H*H, cb + l*H, gm + l*H, bt + l*H,
            dW1, db1, dW2, db2, out, l == NL-1);
    }
}

// Round 11
// 151.638 us; speedup vs baseline: 3.1646x; 1.0233x over previous
//
#include <hip/hip_runtime.h>
#include <hip/hip_bf16.h>
#include <math.h>

// Problem constants (from reference)
#define NN  20000      // nodes
#define NE  50000      // directed edges (undirected -> 2*NE)
#define NE2 100000
#define H   32
#define FN  4
#define FE  2
#define FO  4
#define NL  3

#define FRAGS_PER_LAYER (33 * 2)                   // 33 K-steps x 2 n-tiles
#define BVALS_PER_LAYER (FRAGS_PER_LAYER * 512)    // 33792 bf16 per layer

#define NB_PREP ((NL * BVALS_PER_LAYER + 255)/256)  // 396
#define NB_ZERO (NN * H / 4 / 256)                  // 625
#define NB_ENC  ((NN + 255)/256)                    // 79

#define TCHUNKS 196                                 // 256-edge tiles per direction
#define EB      256

typedef __attribute__((ext_vector_type(8))) short short8;
typedef __attribute__((ext_vector_type(4))) float f32x4;
typedef __attribute__((ext_vector_type(4))) unsigned int u32x4;

__device__ __forceinline__ float gelu_f(float x) {
    return 0.5f * x * (1.0f + erff(x * 0.7071067811865476f));
}
__device__ __forceinline__ short f2bf(float x) {
    __hip_bfloat16 b = __float2bfloat16(x);
    return __builtin_bit_cast(short, b);
}
// gfx950 packed f32->bf16 (RNE), 1 inst per 2 values. No builtin; guide T12 recipe.
__device__ __forceinline__ unsigned int cvt_pk_bf16(float lo, float hi) {
    unsigned int r;
    asm("v_cvt_pk_bf16_f32 %0, %1, %2" : "=v"(r) : "v"(lo), "v"(hi));
    return r;
}

// ---------------------------------------------------------------------------
// Fused prologue: [prep_bfrag | zero_agg | encoder] by blockIdx range.
// ---------------------------------------------------------------------------
__global__ __launch_bounds__(256) void prologue(
    const float* __restrict__ x, const float* __restrict__ pm,
    const float* __restrict__ W_in, const float* __restrict__ b_in,
    const float* __restrict__ mW1, const float* __restrict__ mb1,
    const float* __restrict__ mW2, const float* __restrict__ mb2,
    const float* __restrict__ eW2, const float* __restrict__ eb2,
    float* __restrict__ h, float* __restrict__ agg,
    short* __restrict__ Bhi)
{
    int bid = blockIdx.x;
    int tid = threadIdx.x;

    if (bid < NB_PREP) {
        // ---- prep_bfrag: W2 (+b2 as 33rd step) -> MFMA B-fragment order (bf16)
        int idx = bid * 256 + tid;
        if (idx >= NL * BVALS_PER_LAYER) return;
        int layer = idx / BVALS_PER_LAYER;
        int rem   = idx - layer * BVALS_PER_LAYER;
        int f      = rem >> 9;
        int within = rem & 511;
        int step = f >> 1, nt = f & 1;
        int l = within >> 3, j = within & 7;
        int p = ((l >> 4) << 3) + j;       // K-slot within step == h index
        int n = nt * 16 + (l & 15);        // output column
        float v;
        if (step < 32) v = eW2[layer * 32768 + step * 1024 + p * 32 + n];
        else           v = eb2[layer * 1024 + p * 32 + n];
        Bhi[idx] = f2bf(v);
        return;
    }
    bid -= NB_PREP;

    if (bid < NB_ZERO) {
        int i = bid * 256 + tid;
        ((float4*)agg)[i] = make_float4(0.f, 0.f, 0.f, 0.f);
        return;
    }
    bid -= NB_ZERO;

    // ---- encoder: h = x@W_in + b_in + gelu(pm@mW1+mb1)@mW2 + mb2
    __shared__ float sWin[FN*H], sW1[FN*H], sW2[H*H];
    __shared__ float sbin[H], sb1[H], sb2[H];
    for (int i = tid; i < FN*H; i += 256) { sWin[i] = W_in[i]; sW1[i] = mW1[i]; }
    for (int i = tid; i < H*H; i += 256) sW2[i] = mW2[i];
    if (tid < H) { sbin[tid] = b_in[tid]; sb1[tid] = mb1[tid]; sb2[tid] = mb2[tid]; }
    __syncthreads();
    int n = bid * 256 + tid;
    if (n >= NN) return;
    float xv[FN], pv[FN];
#pragma unroll
    for (int i = 0; i < FN; ++i) { xv[i] = x[n*FN+i]; pv[i] = pm[n*FN+i]; }
    float m[H];
#pragma unroll
    for (int j = 0; j < H; ++j) {
        float a = sb1[j];
#pragma unroll
        for (int i = 0; i < FN; ++i) a += pv[i] * sW1[i*H+j];
        m[j] = gelu_f(a);
    }
#pragma unroll
    for (int j = 0; j < H; ++j) {
        float a = sbin[j] + sb2[j];
#pragma unroll
        for (int i = 0; i < FN; ++i) a += xv[i] * sWin[i*H+j];
        float s = 0.f;
#pragma unroll
        for (int k = 0; k < H; ++k) s += m[k] * sW2[k*H+j];
        h[n*H+j] = a + s;
    }
}

// ---------------------------------------------------------------------------
// Edge pass: 256 threads = 4 waves; 64 edges per wave (4 MFMA M-tiles).
// t computed in-kernel; B bf16 prefetched 2 steps deep; A-fragment built
// with v_cvt_pk_bf16_f32 (4 inst instead of ~40 soft-RNE per 8 values).
// atomicAdd scatter into agg[dst].
// ---------------------------------------------------------------------------
__global__ __launch_bounds__(256) void edge_pass(
    const float* __restrict__ h,
    const int* __restrict__ ei,           // [2, NE] int32
    const float* __restrict__ ea,         // [NE, 2]
    const float* __restrict__ w1,         // eW1 + l*FE*H : [2][32]
    const float* __restrict__ b1,         // eb1 + l*H    : [32]
    const short* __restrict__ Bhi,        // layer fragment stream (bf16)
    float* __restrict__ agg)              // [NN, 32]
{
    __shared__ float t_lds[32][EB];       // 32 KB  [k][edge-in-block]
    __shared__ int src_lds[EB], dst_lds[EB];
    __shared__ float sw[3*H];             // w1 row0, w1 row1, b1

    int tid = threadIdx.x;
    int bid = blockIdx.x;
    bool half2 = bid >= TCHUNKS;
    int er_base = (half2 ? bid - TCHUNKS : bid) * EB;

    if (tid < H) {
        sw[tid]       = w1[tid];
        sw[H + tid]   = w1[H + tid];
        sw[2*H + tid] = b1[tid];
    }
    {   // src/dst for this block's 256 edges
        int er = er_base + tid;
        int erc = er < NE ? er : NE - 1;
        int s, d;
        if (half2) { s = ei[NE + erc]; d = ei[erc]; }
        else       { s = ei[erc];      d = ei[NE + erc]; }
        bool v = er < NE;
        src_lds[tid] = v ? s : 0;
        dst_lds[tid] = v ? d : 0;
    }
    __syncthreads();

    {   // t-gen, all threads parallel: t[k][tid] = gelu(ea[er]@w1 + b1)[k]
        int er = er_base + tid;
        int erc = er < NE ? er : NE - 1;
        float2 av = *(const float2*)(ea + (size_t)erc * 2);
#pragma unroll 8
        for (int k = 0; k < 32; ++k) {
            t_lds[k][tid] = gelu_f(av.x * sw[k] + av.y * sw[H + k] + sw[2*H + k]);
        }
    }
    __syncthreads();

    int wv = tid >> 6, lane = tid & 63;
    int lg = lane >> 4, lm = lane & 15;
    int jbase = wv * 64;

    // Per-lane h[src] slice: 8 f32 features for each of 4 M-tile edges.
    float hs[4][8];
#pragma unroll
    for (int m = 0; m < 4; ++m) {
        int s = src_lds[jbase + m*16 + lm];
        const float4* hp = (const float4*)(h + (size_t)s*H + lg*8);
        float4 u0 = hp[0], u1 = hp[1];
        hs[m][0]=u0.x; hs[m][1]=u0.y; hs[m][2]=u0.z; hs[m][3]=u0.w;
        hs[m][4]=u1.x; hs[m][5]=u1.y; hs[m][6]=u1.z; hs[m][7]=u1.w;
    }

    f32x4 acc[4][2];
#pragma unroll
    for (int m = 0; m < 4; ++m) {
        acc[m][0] = (f32x4){0.f,0.f,0.f,0.f};
        acc[m][1] = (f32x4){0.f,0.f,0.f,0.f};
    }

    // B fragments, 2-step-deep register pipeline: A=step s, B=s+1, C=s+2.
    const short8* F = (const short8*)Bhi;     // frag(step,nt) = F[step*128 + nt*64 + lane]
    short8 A0 = F[lane],        A1 = F[64 + lane];
    short8 B0 = F[128 + lane],  B1 = F[192 + lane];
    short8 C0, C1;

#pragma unroll 1
    for (int step = 0; step < 32; ++step) {
        if (step + 2 <= 32) {                 // issue loads for step+2
            int fo = (step + 2) * 128 + lane;
            C0 = F[fo]; C1 = F[fo + 64];
        }
#pragma unroll
        for (int m = 0; m < 4; ++m) {
            float tv = t_lds[step][jbase + m*16 + lm];
            u32x4 pr;
            pr[0] = cvt_pk_bf16(tv * hs[m][0], tv * hs[m][1]);
            pr[1] = cvt_pk_bf16(tv * hs[m][2], tv * hs[m][3]);
            pr[2] = cvt_pk_bf16(tv * hs[m][4], tv * hs[m][5]);
            pr[3] = cvt_pk_bf16(tv * hs[m][6], tv * hs[m][7]);
            short8 a = __builtin_bit_cast(short8, pr);
            acc[m][0] = __builtin_amdgcn_mfma_f32_16x16x32_bf16(a, A0, acc[m][0], 0, 0, 0);
            acc[m][1] = __builtin_amdgcn_mfma_f32_16x16x32_bf16(a, A1, acc[m][1], 0, 0, 0);
        }
        A0 = B0; A1 = B1; B0 = C0; B1 = C1;
    }
    // peeled bias step (t == 1): A = bf16(hs) directly; uses step-32 frags in A0/A1
#pragma unroll
    for (int m = 0; m < 4; ++m) {
        u32x4 pr;
        pr[0] = cvt_pk_bf16(hs[m][0], hs[m][1]);
        pr[1] = cvt_pk_bf16(hs[m][2], hs[m][3]);
        pr[2] = cvt_pk_bf16(hs[m][4], hs[m][5]);
        pr[3] = cvt_pk_bf16(hs[m][6], hs[m][7]);
        short8 a = __builtin_bit_cast(short8, pr);
        acc[m][0] = __builtin_amdgcn_mfma_f32_16x16x32_bf16(a, A0, acc[m][0], 0, 0, 0);
        acc[m][1] = __builtin_amdgcn_mfma_f32_16x16x32_bf16(a, A1, acc[m][1], 0, 0, 0);
    }

    // C/D layout: col = lane&15, row = (lane>>4)*4 + reg
#pragma unroll
    for (int m = 0; m < 4; ++m) {
#pragma unroll
        for (int r = 0; r < 4; ++r) {
            int erow = jbase + m*16 + lg*4 + r;
            if (er_base + erow < NE) {
                int d = dst_lds[erow];
                atomicAdd(agg + (size_t)d*H + lm,      acc[m][0][r]);
                atomicAdd(agg + (size_t)d*H + 16 + lm, acc[m][1][r]);
            }
        }
    }
}

// ---------------------------------------------------------------------------
// Node update: hc = agg + h@Wr + cb; LayerNorm; h += gelu(hn).
// Non-last: writes h, re-zeros agg. Last: fuses decoder, writes out.
// ---------------------------------------------------------------------------
__global__ __launch_bounds__(256) void node_update(
    float* __restrict__ h, float* __restrict__ agg,
    const float* __restrict__ wr, const float* __restrict__ cb,
    const float* __restrict__ gamma, const float* __restrict__ beta,
    const float* __restrict__ dW1, const float* __restrict__ db1,
    const float* __restrict__ dW2, const float* __restrict__ db2,
    float* __restrict__ out, int last)
{
    __shared__ float swr[H*H], sW1d[H*H], sW2d[H*FO];
    __shared__ float scb[H], sg[H], sb[H], sb1d[H], sb2d[FO];
    int tid = threadIdx.x;
    for (int i = tid; i < H*H; i += 256) { swr[i] = wr[i]; sW1d[i] = dW1[i]; }
    for (int i = tid; i < H*FO; i += 256) sW2d[i] = dW2[i];
    if (tid < H) { scb[tid] = cb[tid]; sg[tid] = gamma[tid]; sb[tid] = beta[tid]; sb1d[tid] = db1[tid]; }
    if (tid < FO) sb2d[tid] = db2[tid];
    __syncthreads();
    int n = blockIdx.x * 256 + tid;
    if (n >= NN) return;

    float hv[H], hc[H];
#pragma unroll
    for (int q = 0; q < 8; ++q) {
        float4 v = ((const float4*)(h + n*H))[q];
        hv[q*4+0]=v.x; hv[q*4+1]=v.y; hv[q*4+2]=v.z; hv[q*4+3]=v.w;
        float4 g = ((const float4*)(agg + n*H))[q];
        hc[q*4+0]=g.x; hc[q*4+1]=g.y; hc[q*4+2]=g.z; hc[q*4+3]=g.w;
    }
#pragma unroll
    for (int o = 0; o < H; ++o) hc[o] += scb[o];
#pragma unroll
    for (int k = 0; k < H; ++k) {
        float hk = hv[k];
#pragma unroll
        for (int o = 0; o < H; ++o) hc[o] += hk * swr[k*H+o];
    }
    float mu = 0.f;
#pragma unroll
    for (int o = 0; o < H; ++o) mu += hc[o];
    mu *= (1.0f/H);
    float var = 0.f;
#pragma unroll
    for (int o = 0; o < H; ++o) { float d = hc[o]-mu; var += d*d; }
    var *= (1.0f/H);
    float rs = rsqrtf(var + 1e-5f);
#pragma unroll
    for (int o = 0; o < H; ++o) {
        float hn = (hc[o]-mu)*rs*sg[o] + sb[o];
        hv[o] += gelu_f(hn);
    }

    if (!last) {
#pragma unroll
        for (int q = 0; q < 8; ++q) {
            ((float4*)(h + n*H))[q]   = make_float4(hv[q*4+0], hv[q*4+1], hv[q*4+2], hv[q*4+3]);
            ((float4*)(agg + n*H))[q] = make_float4(0.f, 0.f, 0.f, 0.f);
        }
    } else {
        // fused decoder: out = gelu(hv@dW1+db1)@dW2 + db2
        float g[H];
#pragma unroll
        for (int j = 0; j < H; ++j) {
            float a = sb1d[j];
#pragma unroll
            for (int k = 0; k < H; ++k) a += hv[k] * sW1d[k*H+j];
            g[j] = gelu_f(a);
        }
#pragma unroll
        for (int o = 0; o < FO; ++o) {
            float a = sb2d[o];
#pragma unroll
            for (int k = 0; k < H; ++k) a += g[k] * sW2d[k*FO+o];
            out[n*FO+o] = a;
        }
    }
}

// ---------------------------------------------------------------------------
extern "C" void kernel_launch(void* const* d_in, const int* in_sizes, int n_in,
                              void* d_out, int out_size, void* d_ws, size_t ws_size,
                              hipStream_t stream)
{
    const float* x    = (const float*)d_in[0];
    const float* pm   = (const float*)d_in[1];
    const int*   ei   = (const int*)d_in[2];      // int inputs arrive as int32
    const float* ea   = (const float*)d_in[3];
    const float* W_in = (const float*)d_in[4];
    const float* b_in = (const float*)d_in[5];
    const float* mW1  = (const float*)d_in[6];
    const float* mb1  = (const float*)d_in[7];
    const float* mW2  = (const float*)d_in[8];
    const float* mb2  = (const float*)d_in[9];
    const float* eW1  = (const float*)d_in[10];
    const float* eb1  = (const float*)d_in[11];
    const float* eW2  = (const float*)d_in[12];
    const float* eb2  = (const float*)d_in[13];
    const float* Wr   = (const float*)d_in[14];
    const float* cb   = (const float*)d_in[15];
    const float* gm   = (const float*)d_in[16];
    const float* bt   = (const float*)d_in[17];
    const float* dW1  = (const float*)d_in[18];
    const float* db1  = (const float*)d_in[19];
    const float* dW2  = (const float*)d_in[20];
    const float* db2  = (const float*)d_in[21];
    float* out = (float*)d_out;

    float* h   = (float*)d_ws;                    // NN*H f32
    float* agg = h + NN*H;                        // NN*H f32
    short* Bhi = (short*)(agg + NN*H);            // NL*33792 bf16

    prologue<<<NB_PREP + NB_ZERO + NB_ENC, 256, 0, stream>>>(
        x, pm, W_in, b_in, mW1, mb1, mW2, mb2, eW2, eb2, h, agg, Bhi);

    for (int l = 0; l < NL; ++l) {
        edge_pass<<<2*TCHUNKS, 256, 0, stream>>>(
            h, ei, ea, eW1 + l*FE*H, eb1 + l*H,
            Bhi + l*BVALS_PER_LAYER, agg);
        node_update<<<(NN + 255)/256, 256, 0, stream>>>(
            h, agg, Wr + l*H*H, cb + l*H, gm + l*H, bt + l*H,
            dW1, db1, dW2, db2, out, l == NL-1);
    }
}